// Round 1
// baseline (42884.946 us; speedup 1.0000x reference)
//
#include <hip/hip_runtime.h>
#include <hip/hip_bf16.h>
#include <stdint.h>

// Problem constants
#define B_    128
#define T_    1024
#define IN_   256
#define L_    1024
#define OUT_  256
#define KTOT  1280   // IN_ + L_

// Decomposition: 8 groups x 16 batches; each group = 32 WGs x 32 latent cols.
#define GROUPS 8
#define WPG    32
#define NB     16
#define NC     32
#define PAD_K  1288                      // 1280 + 8 bf16 pad (breaks LDS bank stride)
#define LDS_W_BYTES (NC * PAD_K * 2)     // 82432
#define LDS_TOTAL   (LDS_W_BYTES + 4*2*4*64*4)  // + 8 KB reduce buffer = 90624

using short8 = __attribute__((ext_vector_type(8))) short;
using bf16x8 = __attribute__((ext_vector_type(8))) __bf16;
using f32x4  = __attribute__((ext_vector_type(4))) float;

__device__ __forceinline__ unsigned short f2b(float f) {   // fp32 -> bf16 RNE
  unsigned u = __builtin_bit_cast(unsigned, f);
  u += 0x7FFFu + ((u >> 16) & 1u);
  return (unsigned short)(u >> 16);
}
__device__ __forceinline__ float b2f(unsigned short h) {
  unsigned u = ((unsigned)h) << 16;
  return __builtin_bit_cast(float, u);
}
__device__ __forceinline__ float fast_tanh(float z) {
  z = fminf(fmaxf(z, -30.f), 30.f);
  float e2 = __expf(2.f * z);
  return __fdividef(e2 - 1.f, e2 + 1.f);
}

// Group barrier: release all prior stores, arrive on group counter, spin, acquire.
__device__ __forceinline__ void groupBarrier(unsigned int* cnt, unsigned int target) {
  __threadfence();            // publish our h stores (agent scope)
  __syncthreads();
  if (threadIdx.x == 0) {
    __hip_atomic_fetch_add(cnt, 1u, __ATOMIC_RELEASE, __HIP_MEMORY_SCOPE_AGENT);
    while (__hip_atomic_load(cnt, __ATOMIC_ACQUIRE, __HIP_MEMORY_SCOPE_AGENT) < target) {
      __builtin_amdgcn_s_sleep(1);
    }
  }
  __syncthreads();
  __threadfence();            // invalidate stale caches before reading peers' h
}

__global__ __launch_bounds__(256, 1)
void rnn_persistent(const float* __restrict__ x, const float* __restrict__ Wlin,
                    unsigned short* __restrict__ h0buf, unsigned short* __restrict__ h1buf,
                    unsigned int* __restrict__ counters)
{
  extern __shared__ char smem[];
  short* Wlds = (short*)smem;                       // [NC][PAD_K] bf16
  float* red  = (float*)(smem + LDS_W_BYTES);       // [4 waves][2 tiles][4 regs][64 lanes]

  const int tid = threadIdx.x;
  const int g   = blockIdx.x & 7;       // group (intended: one XCD per group)
  const int w   = blockIdx.x >> 3;      // 0..31: which col slice
  const int bb  = g * NB;               // first batch of group
  const int cc  = w * NC;               // first latent col of this WG
  unsigned int* cnt = counters + g * 64;   // 256 B spacing per group

  // ---- one-time: stage this WG's weight rows (bf16) into LDS ----
  for (int r = 0; r < NC; ++r) {
    const float* wrow = Wlin + (size_t)(cc + r) * KTOT;
    for (int k = tid; k < KTOT; k += 256)
      Wlds[r * PAD_K + k] = (short)f2b(wrow[k]);
  }
  // ---- zero our slice of h buffer 0 ----
  for (int i = tid; i < NB * NC; i += 256) {
    int b = bb + (i >> 5), c = cc + (i & 31);
    h0buf[b * L_ + c] = 0;
  }
  groupBarrier(cnt, WPG * 1);

  const int wv   = tid >> 6;            // wave 0..3 (K-split)
  const int l    = tid & 63;
  const int lrow = l & 15;              // M-row (A) / N-col (B) within tile
  const int lk   = (l >> 4) * 8;        // K offset within k-step

  for (int t = 0; t < T_; ++t) {
    const unsigned short* hcur = (t & 1) ? h1buf : h0buf;
    unsigned short*       hnxt = (t & 1) ? h0buf : h1buf;

    f32x4 acc0 = {0.f, 0.f, 0.f, 0.f};
    f32x4 acc1 = {0.f, 0.f, 0.f, 0.f};

    #pragma unroll
    for (int j = 0; j < 10; ++j) {
      const int kk    = wv + 4 * j;       // k-step 0..39 (0..7 = x region, 8..39 = h)
      const int kbase = kk * 32 + lk;
      short8 a;
      if (kk < 8) {   // x region: load 8 fp32, convert
        const float* xp = x + ((size_t)(bb + lrow) * T_ + t) * IN_ + kbase;
        f32x4 x0 = *(const f32x4*)xp;
        f32x4 x1 = *(const f32x4*)(xp + 4);
        a[0] = (short)f2b(x0[0]); a[1] = (short)f2b(x0[1]);
        a[2] = (short)f2b(x0[2]); a[3] = (short)f2b(x0[3]);
        a[4] = (short)f2b(x1[0]); a[5] = (short)f2b(x1[1]);
        a[6] = (short)f2b(x1[2]); a[7] = (short)f2b(x1[3]);
      } else {        // h region: bf16 direct
        a = *(const short8*)(hcur + (size_t)(bb + lrow) * L_ + (kbase - IN_));
      }
      short8 b0 = *(const short8*)&Wlds[lrow        * PAD_K + kbase];
      short8 b1 = *(const short8*)&Wlds[(lrow + 16) * PAD_K + kbase];
      acc0 = __builtin_amdgcn_mfma_f32_16x16x32_bf16(
               __builtin_bit_cast(bf16x8, a), __builtin_bit_cast(bf16x8, b0), acc0, 0, 0, 0);
      acc1 = __builtin_amdgcn_mfma_f32_16x16x32_bf16(
               __builtin_bit_cast(bf16x8, a), __builtin_bit_cast(bf16x8, b1), acc1, 0, 0, 0);
    }

    // ---- cross-wave K reduction via LDS ----
    #pragma unroll
    for (int j = 0; j < 4; ++j) {
      red[((wv * 2 + 0) * 4 + j) * 64 + l] = acc0[j];
      red[((wv * 2 + 1) * 4 + j) * 64 + l] = acc1[j];
    }
    __syncthreads();
    if (wv < 2) {
      const int tile = wv;
      #pragma unroll
      for (int j = 0; j < 4; ++j) {
        float s = red[((0 * 2 + tile) * 4 + j) * 64 + l]
                + red[((1 * 2 + tile) * 4 + j) * 64 + l]
                + red[((2 * 2 + tile) * 4 + j) * 64 + l]
                + red[((3 * 2 + tile) * 4 + j) * 64 + l];
        float hv = fast_tanh(s);
        // C/D layout (verified m89): col = lane&15, row = (lane>>4)*4 + reg
        int row = bb + (l >> 4) * 4 + j;
        int col = cc + tile * 16 + (l & 15);
        hnxt[row * L_ + col] = (unsigned short)f2b(hv);
      }
    }
    if (t < T_ - 1) groupBarrier(cnt, WPG * (t + 2));
  }
}

__global__ __launch_bounds__(256)
void decode_kernel(const unsigned short* __restrict__ hfin,
                   const float* __restrict__ Wdec, const float* __restrict__ bdec,
                   float* __restrict__ out)
{
  __shared__ float hrow[L_];
  const int b = blockIdx.x, tid = threadIdx.x;
  for (int k = tid; k < L_; k += 256)
    hrow[k] = b2f(hfin[b * L_ + k]);
  __syncthreads();
  float s = bdec[tid];
  const float* wr = Wdec + (size_t)tid * L_;
  #pragma unroll 4
  for (int k = 0; k < L_; k += 4) {
    f32x4 wq = *(const f32x4*)(wr + k);
    s += hrow[k] * wq[0] + hrow[k+1] * wq[1] + hrow[k+2] * wq[2] + hrow[k+3] * wq[3];
  }
  out[b * OUT_ + tid] = fast_tanh(s);
}

extern "C" void kernel_launch(void* const* d_in, const int* in_sizes, int n_in,
                              void* d_out, int out_size, void* d_ws, size_t ws_size,
                              hipStream_t stream)
{
  const float* x    = (const float*)d_in[0];
  const float* Wlin = (const float*)d_in[1];
  const float* Wdec = (const float*)d_in[2];
  const float* bdec = (const float*)d_in[3];
  float* out = (float*)d_out;

  // ws layout: h double buffer (2 x 128x1024 bf16 = 512 KB), then group counters.
  unsigned short* h0 = (unsigned short*)d_ws;
  unsigned short* h1 = h0 + (size_t)B_ * L_;
  unsigned int* counters = (unsigned int*)((char*)d_ws + (size_t)2 * B_ * L_ * 2);

  hipMemsetAsync(counters, 0, GROUPS * 64 * sizeof(unsigned int), stream);

  static bool attr_set = false;
  (void)attr_set;
  hipFuncSetAttribute((const void*)rnn_persistent,
                      hipFuncAttributeMaxDynamicSharedMemorySize, LDS_TOTAL);

  hipLaunchKernelGGL(rnn_persistent, dim3(GROUPS * WPG), dim3(256), LDS_TOTAL, stream,
                     x, Wlin, h0, h1, counters);
  hipLaunchKernelGGL(decode_kernel, dim3(B_), dim3(256), 0, stream,
                     h0, Wdec, bdec, out);
}

// Round 2
// 3289.983 us; speedup vs baseline: 13.0350x; 13.0350x over previous
//
#include <hip/hip_runtime.h>
#include <hip/hip_bf16.h>
#include <stdint.h>

// Problem constants
#define B_    128
#define T_    1024
#define IN_   256
#define L_    1024
#define OUT_  256
#define KTOT  1280   // IN_ + L_

// Decomposition: 8 groups x 16 batches; each group = 32 WGs x 32 latent cols.
#define GROUPS 8
#define WPG    32
#define NB     16
#define NC     32
#define PAD_K  1288                       // 1280 + 8 bf16 pad
#define LDS_W_BYTES (NC * PAD_K * 2)      // 82432
#define RED_BYTES   (8 * 4 * 64 * 4)      // 8192: [4 waves][2 tiles][4 regs][64 lanes]
#define STILE_BYTES (16 * 32 * 2)         // 1024: assembled output tile
#define LDS_TOTAL   (LDS_W_BYTES + RED_BYTES + STILE_BYTES)   // 91648

using short8 = __attribute__((ext_vector_type(8))) short;
using bf16x8 = __attribute__((ext_vector_type(8))) __bf16;
using f32x4  = __attribute__((ext_vector_type(4))) float;

__device__ __forceinline__ unsigned short f2b(float f) {   // fp32 -> bf16 RNE
  unsigned u = __builtin_bit_cast(unsigned, f);
  u += 0x7FFFu + ((u >> 16) & 1u);
  return (unsigned short)(u >> 16);
}
__device__ __forceinline__ float b2f(unsigned short h) {
  unsigned u = ((unsigned)h) << 16;
  return __builtin_bit_cast(float, u);
}
__device__ __forceinline__ float fast_tanh(float z) {
  z = fminf(fmaxf(z, -30.f), 30.f);
  float e2 = __expf(2.f * z);
  return __fdividef(e2 - 1.f, e2 + 1.f);
}

__global__ __launch_bounds__(256, 1)
void rnn_persistent(const float* __restrict__ x, const float* __restrict__ Wlin,
                    unsigned short* __restrict__ h0buf, unsigned short* __restrict__ h1buf,
                    unsigned int* __restrict__ flags)
{
  extern __shared__ char smem[];
  short* Wlds = (short*)smem;                                   // [NC][PAD_K] bf16
  float* red  = (float*)(smem + LDS_W_BYTES);                   // reduce buffer
  unsigned short* stile = (unsigned short*)(smem + LDS_W_BYTES + RED_BYTES); // [16][32]

  const int tid = threadIdx.x;
  const int g   = blockIdx.x & 7;       // group (one per XCD under round-robin; perf only)
  const int w   = blockIdx.x >> 3;      // 0..31: col slice
  const int bb  = g * NB;
  const int cc  = w * NC;
  unsigned int* myflag = flags + (size_t)(g * WPG + w) * 16;    // 64 B apart

  // ---- one-time: stage this WG's weight rows (bf16) into LDS ----
  for (int r = 0; r < NC; ++r) {
    const float* wrow = Wlin + (size_t)(cc + r) * KTOT;
    for (int k = tid; k < KTOT; k += 256)
      Wlds[r * PAD_K + k] = (short)f2b(wrow[k]);
  }
  __syncthreads();

  const int wv   = tid >> 6;            // wave 0..3 (K-split)
  const int l    = tid & 63;
  const int lrow = l & 15;              // M-row (A) / N-col (B) within tile
  const int lk   = (l >> 4) * 8;        // K offset within k-step

  for (int t = 0; t < T_; ++t) {
    // read buffer index t&1 holds h_t input; write buffer holds h_{t+1}
    const unsigned short* hcur = (t & 1) ? h1buf : h0buf;
    unsigned short*       hnxt = (t & 1) ? h0buf : h1buf;

    f32x4 acc0 = {0.f, 0.f, 0.f, 0.f};
    f32x4 acc1 = {0.f, 0.f, 0.f, 0.f};

    // ---- x part (kk = wv, wv+4 in 0..7): normal cached loads; overlaps flag wait ----
    #pragma unroll
    for (int j = 0; j < 2; ++j) {
      const int kk    = wv + 4 * j;
      const int kbase = kk * 32 + lk;
      const float* xp = x + ((size_t)(bb + lrow) * T_ + t) * IN_ + kbase;
      f32x4 x0 = *(const f32x4*)xp;
      f32x4 x1 = *(const f32x4*)(xp + 4);
      short8 a;
      a[0] = (short)f2b(x0[0]); a[1] = (short)f2b(x0[1]);
      a[2] = (short)f2b(x0[2]); a[3] = (short)f2b(x0[3]);
      a[4] = (short)f2b(x1[0]); a[5] = (short)f2b(x1[1]);
      a[6] = (short)f2b(x1[2]); a[7] = (short)f2b(x1[3]);
      short8 b0 = *(const short8*)&Wlds[lrow        * PAD_K + kbase];
      short8 b1 = *(const short8*)&Wlds[(lrow + 16) * PAD_K + kbase];
      acc0 = __builtin_amdgcn_mfma_f32_16x16x32_bf16(
               __builtin_bit_cast(bf16x8, a), __builtin_bit_cast(bf16x8, b0), acc0, 0, 0, 0);
      acc1 = __builtin_amdgcn_mfma_f32_16x16x32_bf16(
               __builtin_bit_cast(bf16x8, a), __builtin_bit_cast(bf16x8, b1), acc1, 0, 0, 0);
    }

    // ---- h part (t=0: h is zero, skip entirely) ----
    if (t > 0) {
      // Wait for all 32 group members to have published step t-1's output.
      // Arrival was a plain device-scope store of value t; no RMW, no reset needed.
      if (wv == 0) {
        unsigned int* fp = flags + (size_t)(g * WPG + (l & 31)) * 16;
        while (true) {
          unsigned int v = __hip_atomic_load(fp, __ATOMIC_RELAXED, __HIP_MEMORY_SCOPE_AGENT);
          if (__all((int)(v >= (unsigned)t))) break;
          __builtin_amdgcn_s_sleep(1);
        }
      }
      __syncthreads();

      // Issue all 8 h-fragment loads, device-coherent (bypass L1/L2 -> L3).
      short8 hf[8];
      #pragma unroll
      for (int j = 2; j < 10; ++j) {
        const int kk    = wv + 4 * j;
        const int kbase = kk * 32 + lk - IN_;
        const unsigned short* p = hcur + (size_t)(bb + lrow) * L_ + kbase;
        asm volatile("global_load_dwordx4 %0, %1, off sc0 sc1"
                     : "=v"(hf[j - 2]) : "v"(p) : "memory");
      }
      asm volatile("s_waitcnt vmcnt(0)" ::: "memory");
      __builtin_amdgcn_sched_barrier(0);

      #pragma unroll
      for (int j = 2; j < 10; ++j) {
        const int kbase = (wv + 4 * j) * 32 + lk;
        short8 b0 = *(const short8*)&Wlds[lrow        * PAD_K + kbase];
        short8 b1 = *(const short8*)&Wlds[(lrow + 16) * PAD_K + kbase];
        acc0 = __builtin_amdgcn_mfma_f32_16x16x32_bf16(
                 __builtin_bit_cast(bf16x8, hf[j - 2]), __builtin_bit_cast(bf16x8, b0), acc0, 0, 0, 0);
        acc1 = __builtin_amdgcn_mfma_f32_16x16x32_bf16(
                 __builtin_bit_cast(bf16x8, hf[j - 2]), __builtin_bit_cast(bf16x8, b1), acc1, 0, 0, 0);
      }
    }

    // ---- cross-wave K reduction via LDS ----
    #pragma unroll
    for (int j = 0; j < 4; ++j) {
      red[((wv * 2 + 0) * 4 + j) * 64 + l] = acc0[j];
      red[((wv * 2 + 1) * 4 + j) * 64 + l] = acc1[j];
    }
    __syncthreads();
    if (wv < 2) {
      const int tile = wv;
      #pragma unroll
      for (int j = 0; j < 4; ++j) {
        float s = red[((0 * 2 + tile) * 4 + j) * 64 + l]
                + red[((1 * 2 + tile) * 4 + j) * 64 + l]
                + red[((2 * 2 + tile) * 4 + j) * 64 + l]
                + red[((3 * 2 + tile) * 4 + j) * 64 + l];
        float hv = fast_tanh(s);
        // C/D layout: col = lane&15, row = (lane>>4)*4 + reg
        const int row = (l >> 4) * 4 + j;
        const int col = tile * 16 + (l & 15);
        stile[row * 32 + col] = f2b(hv);
      }
    }
    __syncthreads();

    // ---- publish tile: 256 dword stores, device-coherent ----
    {
      const int row  = tid >> 4;
      const int dcol = tid & 15;
      unsigned int v = ((const unsigned int*)stile)[tid];
      unsigned int* dp = (unsigned int*)(hnxt + (size_t)(bb + row) * L_ + cc) + dcol;
      asm volatile("global_store_dword %0, %1, off sc0 sc1" :: "v"(dp), "v"(v) : "memory");
    }
    asm volatile("s_waitcnt vmcnt(0)" ::: "memory");
    __syncthreads();   // all 4 waves' stores drained before the flag goes up
    if (tid == 0)
      __hip_atomic_store(myflag, (unsigned)(t + 1), __ATOMIC_RELAXED, __HIP_MEMORY_SCOPE_AGENT);
  }
}

__global__ __launch_bounds__(256)
void decode_kernel(const unsigned short* __restrict__ hfin,
                   const float* __restrict__ Wdec, const float* __restrict__ bdec,
                   float* __restrict__ out)
{
  __shared__ float hrow[L_];
  const int b = blockIdx.x, tid = threadIdx.x;
  for (int k = tid; k < L_; k += 256)
    hrow[k] = b2f(hfin[b * L_ + k]);
  __syncthreads();
  float s = bdec[tid];
  const float* wr = Wdec + (size_t)tid * L_;
  #pragma unroll 4
  for (int k = 0; k < L_; k += 4) {
    f32x4 wq = *(const f32x4*)(wr + k);
    s += hrow[k] * wq[0] + hrow[k+1] * wq[1] + hrow[k+2] * wq[2] + hrow[k+3] * wq[3];
  }
  out[b * OUT_ + tid] = fast_tanh(s);
}

extern "C" void kernel_launch(void* const* d_in, const int* in_sizes, int n_in,
                              void* d_out, int out_size, void* d_ws, size_t ws_size,
                              hipStream_t stream)
{
  const float* x    = (const float*)d_in[0];
  const float* Wlin = (const float*)d_in[1];
  const float* Wdec = (const float*)d_in[2];
  const float* bdec = (const float*)d_in[3];
  float* out = (float*)d_out;

  // ws layout: h double buffer (2 x 128x1024 bf16 = 512 KB), then flag array (16 KB).
  unsigned short* h0 = (unsigned short*)d_ws;
  unsigned short* h1 = h0 + (size_t)B_ * L_;
  unsigned int* flags = (unsigned int*)((char*)d_ws + (size_t)2 * B_ * L_ * 2);

  hipMemsetAsync(flags, 0, (size_t)GROUPS * WPG * 16 * sizeof(unsigned int), stream);

  hipFuncSetAttribute((const void*)rnn_persistent,
                      hipFuncAttributeMaxDynamicSharedMemorySize, LDS_TOTAL);

  hipLaunchKernelGGL(rnn_persistent, dim3(GROUPS * WPG), dim3(256), LDS_TOTAL, stream,
                     x, Wlin, h0, h1, flags);
  // final h = output of step 1023, written to buffer parity (1023+1)&1 = 0
  hipLaunchKernelGGL(decode_kernel, dim3(B_), dim3(256), 0, stream,
                     h0, Wdec, bdec, out);
}